// Round 1
// baseline (1285.821 us; speedup 1.0000x reference)
//
#include <hip/hip_runtime.h>

#define T_ 1024
#define H_ 32
#define P_ 64
#define N_ 128
#define L_ 64
#define K_ 16

// ---------------------------------------------------------------------------
// Kernel 1: global inclusive cumsum of A over t, per (b,h).
// cumA[bh*T + t] = sum_{m<=t} A[b,m,h]
// ---------------------------------------------------------------------------
__global__ __launch_bounds__(1024) void cuma_kernel(const float* __restrict__ A,
                                                    float* __restrict__ cumA) {
  const int bh = blockIdx.x;            // 0..63   (b*32 + h)
  const int b = bh >> 5, h = bh & 31;
  const int t = threadIdx.x;            // 0..1023
  __shared__ float s[1024];
  s[t] = A[(b * T_ + t) * H_ + h];
  __syncthreads();
  // Hillis-Steele scan
  for (int off = 1; off < 1024; off <<= 1) {
    float v = (t >= off) ? s[t - off] : 0.0f;
    __syncthreads();
    s[t] += v;
    __syncthreads();
  }
  cumA[bh * T_ + t] = s[t];
}

// ---------------------------------------------------------------------------
// Kernel 2: causal weighted attention.
// Y[t,p] = sum_{j<=t} (C_t . B_j) * (exp(cumA_t - cumA_j) + msf*mask[t,j]) * x[j,p]
// One workgroup per (query-chunk, bh). 256 threads, 4x4 register blocking.
// ---------------------------------------------------------------------------
__global__ __launch_bounds__(256) void attn_kernel(
    const float* __restrict__ x, const float* __restrict__ Bm,
    const float* __restrict__ Cm, const float* __restrict__ mask,
    const float* __restrict__ msf_p, const float* __restrict__ cumA,
    float* __restrict__ Y) {
  const int qc = 15 - (int)blockIdx.x;   // heavy blocks first (causal imbalance)
  const int bh = blockIdx.y;             // b*32 + h
  const int b = bh >> 5, h = bh & 31;
  const float msf = msf_p[0];

  // +4 padding keeps float4 alignment; stride 132 -> bank stride 4 for the
  // interleaved-j B reads (2-way, free per m136).
  __shared__ float Cs[64][132];   // C[query row][k]
  __shared__ float Bs[64][132];   // B[key row][k]
  __shared__ float Xs[64][68];    // x[key row][p]
  __shared__ float Ps[64][68];    // P^T: Ps[j][i]
  __shared__ float cAq[64];
  __shared__ float cAk[64];

  const int tid = threadIdx.x;
  const int ti = tid >> 4, tj = tid & 15;
  const int i0 = ti * 4;   // S rows / Y rows: i0..i0+3
  const int p0 = tj * 4;   // Y cols: p0..p0+3
  // S cols are interleaved: j = tj + 16*c, c = 0..3 (spreads LDS banks)

  float acc[4][4];
#pragma unroll
  for (int r = 0; r < 4; ++r)
#pragma unroll
    for (int c = 0; c < 4; ++c) acc[r][c] = 0.0f;

  // stage C tile (reused across all key tiles) + query cumA
  {
    const float* Cg = Cm + ((size_t)(b * T_ + qc * L_) * H_ + h) * N_;
    for (int e = tid; e < 64 * 32; e += 256) {
      const int row = e >> 5, k4 = e & 31;
      *(float4*)&Cs[row][k4 * 4] =
          *(const float4*)(Cg + (size_t)row * (H_ * N_) + k4 * 4);
    }
    if (tid < 64) cAq[tid] = cumA[bh * T_ + qc * L_ + tid];
  }

  for (int kc = 0; kc <= qc; ++kc) {
    __syncthreads();  // previous iteration done with Bs/Xs/Ps
    // ---- stage key tile ----
    {
      const float* Bg = Bm + ((size_t)(b * T_ + kc * L_) * H_ + h) * N_;
      for (int e = tid; e < 64 * 32; e += 256) {
        const int row = e >> 5, k4 = e & 31;
        *(float4*)&Bs[row][k4 * 4] =
            *(const float4*)(Bg + (size_t)row * (H_ * N_) + k4 * 4);
      }
      const float* xg = x + ((size_t)(b * T_ + kc * L_) * H_ + h) * P_;
      for (int e = tid; e < 64 * 16; e += 256) {
        const int row = e >> 4, p4 = e & 15;
        *(float4*)&Xs[row][p4 * 4] =
            *(const float4*)(xg + (size_t)row * (H_ * P_) + p4 * 4);
      }
      if (tid < 64) cAk[tid] = cumA[bh * T_ + kc * L_ + tid];
    }
    __syncthreads();

    // ---- S = C . B^T over k=0..127 ----
    float sv[4][4];
#pragma unroll
    for (int r = 0; r < 4; ++r)
#pragma unroll
      for (int c = 0; c < 4; ++c) sv[r][c] = 0.0f;

#pragma unroll 4
    for (int kk = 0; kk < 128; kk += 4) {
      float4 ca[4], bb[4];
#pragma unroll
      for (int r = 0; r < 4; ++r) ca[r] = *(const float4*)&Cs[i0 + r][kk];
#pragma unroll
      for (int c = 0; c < 4; ++c) bb[c] = *(const float4*)&Bs[tj + 16 * c][kk];
#pragma unroll
      for (int r = 0; r < 4; ++r)
#pragma unroll
        for (int c = 0; c < 4; ++c) {
          sv[r][c] += ca[r].x * bb[c].x + ca[r].y * bb[c].y +
                      ca[r].z * bb[c].z + ca[r].w * bb[c].w;
        }
    }

    // ---- apply weights, write P^T to LDS ----
    const float* mrow = mask + ((size_t)bh * T_ + (size_t)qc * L_) * T_ + (size_t)kc * L_;
    const bool diag = (kc == qc);
#pragma unroll
    for (int r = 0; r < 4; ++r) {
      const int li = i0 + r;
#pragma unroll
      for (int c = 0; c < 4; ++c) {
        const int lj = tj + 16 * c;
        float w = __expf(cAq[li] - cAk[lj]) + msf * mrow[(size_t)li * T_ + lj];
        if (diag && lj > li) w = 0.0f;
        Ps[lj][li] = sv[r][c] * w;
      }
    }
    __syncthreads();

    // ---- Y += P . x ----
#pragma unroll 8
    for (int j = 0; j < 64; ++j) {
      const float4 pv = *(const float4*)&Ps[j][i0];
      const float4 xv = *(const float4*)&Xs[j][p0];
      acc[0][0] += pv.x * xv.x; acc[0][1] += pv.x * xv.y;
      acc[0][2] += pv.x * xv.z; acc[0][3] += pv.x * xv.w;
      acc[1][0] += pv.y * xv.x; acc[1][1] += pv.y * xv.y;
      acc[1][2] += pv.y * xv.z; acc[1][3] += pv.y * xv.w;
      acc[2][0] += pv.z * xv.x; acc[2][1] += pv.z * xv.y;
      acc[2][2] += pv.z * xv.z; acc[2][3] += pv.z * xv.w;
      acc[3][0] += pv.w * xv.x; acc[3][1] += pv.w * xv.y;
      acc[3][2] += pv.w * xv.z; acc[3][3] += pv.w * xv.w;
    }
  }

  // ---- write Y ----
  float* Yg = Y + ((size_t)(b * T_ + qc * L_) * H_ + h) * P_;
#pragma unroll
  for (int r = 0; r < 4; ++r) {
    float4 o;
    o.x = acc[r][0]; o.y = acc[r][1]; o.z = acc[r][2]; o.w = acc[r][3];
    *(float4*)(Yg + (size_t)(i0 + r) * (H_ * P_) + p0) = o;
  }
}

// ---------------------------------------------------------------------------
// Kernel 3: final_state[b,h,p,n] = sum_t exp(cumA_{T-1} - cumA_t) B[t,n] x[t,p]
// ---------------------------------------------------------------------------
__global__ __launch_bounds__(256) void state_kernel(
    const float* __restrict__ x, const float* __restrict__ Bm,
    const float* __restrict__ cumA, float* __restrict__ out) {
  const int bh = blockIdx.x;  // 64
  const int pg = blockIdx.y;  // 4 groups of 16 p
  const int b = bh >> 5, h = bh & 31;
  const int tid = threadIdx.x;
  const int n = tid & 127;
  const int ph = tid >> 7;                 // 0..1
  const int pbase = pg * 16 + ph * 8;

  __shared__ float wsh[1024];
  {
    const float cend = cumA[bh * T_ + (T_ - 1)];
    for (int t = tid; t < 1024; t += 256)
      wsh[t] = __expf(cend - cumA[bh * T_ + t]);
  }
  __syncthreads();

  float acc[8];
#pragma unroll
  for (int pp = 0; pp < 8; ++pp) acc[pp] = 0.0f;

  for (int t = 0; t < T_; ++t) {
    const float bv = Bm[((size_t)(b * T_ + t) * H_ + h) * N_ + n] * wsh[t];
    const float* xp = x + ((size_t)(b * T_ + t) * H_ + h) * P_ + pbase;
#pragma unroll
    for (int pp = 0; pp < 8; ++pp) acc[pp] += bv * xp[pp];
  }

  float* o = out + (size_t)bh * P_ * N_;
#pragma unroll
  for (int pp = 0; pp < 8; ++pp) o[(size_t)(pbase + pp) * N_ + n] = acc[pp];
}

// ---------------------------------------------------------------------------
extern "C" void kernel_launch(void* const* d_in, const int* in_sizes, int n_in,
                              void* d_out, int out_size, void* d_ws, size_t ws_size,
                              hipStream_t stream) {
  const float* x    = (const float*)d_in[0];  // (2,1024,32,64)
  const float* A    = (const float*)d_in[1];  // (2,1024,32)
  const float* Bm   = (const float*)d_in[2];  // (2,1024,32,128)
  const float* Cm   = (const float*)d_in[3];  // (2,1024,32,128)
  const float* mask = (const float*)d_in[4];  // (2,32,1024,1024)
  const float* msf  = (const float*)d_in[5];  // scalar
  float* Y  = (float*)d_out;                               // (2,1024,32,64)
  float* fs = (float*)d_out + (size_t)2 * T_ * H_ * P_;    // (2,32,64,128)
  float* cumA = (float*)d_ws;                              // 64*1024 floats

  cuma_kernel<<<64, 1024, 0, stream>>>(A, cumA);
  attn_kernel<<<dim3(16, 64), 256, 0, stream>>>(x, Bm, Cm, mask, msf, cumA, Y);
  state_kernel<<<dim3(64, 4), 256, 0, stream>>>(x, Bm, cumA, fs);
}

// Round 2
// 539.585 us; speedup vs baseline: 2.3830x; 2.3830x over previous
//
#include <hip/hip_runtime.h>

#define T_ 1024
#define H_ 32
#define P_ 64
#define N_ 128
#define L_ 64

typedef float f32x4 __attribute__((ext_vector_type(4)));
typedef short short8 __attribute__((ext_vector_type(8)));
typedef short short4v __attribute__((ext_vector_type(4)));

// fp32 -> bf16 round-nearest-even (bit-level, no header dependency)
static __device__ __forceinline__ unsigned short f2bf(float f) {
  unsigned int u = __float_as_uint(f);
  u = u + 0x7fffu + ((u >> 16) & 1u);
  return (unsigned short)(u >> 16);
}

// ---------------------------------------------------------------------------
// Kernel 1: global inclusive cumsum of A over t, per (b,h).
// ---------------------------------------------------------------------------
__global__ __launch_bounds__(1024) void cuma_kernel(const float* __restrict__ A,
                                                    float* __restrict__ cumA) {
  const int bh = blockIdx.x;
  const int b = bh >> 5, h = bh & 31;
  const int t = threadIdx.x;
  __shared__ float s[1024];
  s[t] = A[(b * T_ + t) * H_ + h];
  __syncthreads();
  for (int off = 1; off < 1024; off <<= 1) {
    float v = (t >= off) ? s[t - off] : 0.0f;
    __syncthreads();
    s[t] += v;
    __syncthreads();
  }
  cumA[bh * T_ + t] = s[t];
}

// ---------------------------------------------------------------------------
// Kernel 2: causal weighted attention, bf16 MFMA.
// Y[t,p] = sum_{j<=t} (C_t.B_j) * (exp(cumA_t-cumA_j) + msf*mask[t,j]) * x[j,p]
// One block per (query-chunk, bh). 4 waves; wave w owns S/Y rows 16w..16w+15.
// ---------------------------------------------------------------------------
__global__ __launch_bounds__(256, 3) void attn_kernel(
    const float* __restrict__ x, const float* __restrict__ Bm,
    const float* __restrict__ Cm, const float* __restrict__ mask,
    const float* __restrict__ msf_p, const float* __restrict__ cumA,
    float* __restrict__ Y) {
  const int qc = 15 - (int)blockIdx.x;   // heavy blocks first
  const int bh = blockIdx.y;
  const int b = bh >> 5, h = bh & 31;
  const float msf = msf_p[0];

  // bf16 tiles. Row strides are multiples of 8 bf16 (16B) so ds_read_b128
  // fragment loads stay aligned; stride 136 (272B -> bank stride 4) and 72
  // (144B -> bank stride 4) give only 2-way lane aliasing (free, m136).
  __shared__ short Cs[64][136];  // C[query row][k]   bf16
  __shared__ short Bs[64][136];  // B[key row][k]     bf16
  __shared__ short Xt[64][72];   // x^T: Xt[p][key j] bf16
  __shared__ short Ps[64][72];   // P[i][j]           bf16 (per-wave 16-row strips)
  __shared__ float cAq[64];
  __shared__ float cAk[64];

  const int tid = threadIdx.x;
  const int wv = tid >> 6;       // wave 0..3 -> S/Y rows 16*wv..16*wv+15
  const int lane = tid & 63;
  const int q = lane >> 4;       // quad
  const int c = lane & 15;       // col-ish lane index

  // ---- stage C tile (bf16) + query cumA ----
  {
    const float* Cg = Cm + ((size_t)(b * T_ + qc * L_) * H_ + h) * N_;
#pragma unroll
    for (int it = 0; it < 8; ++it) {
      const int idx = tid + 256 * it;        // float4 index, 2048 total
      const int row = idx >> 5, k4 = idx & 31;
      const float4 v = *(const float4*)(Cg + (size_t)row * (H_ * N_) + k4 * 4);
      short4v o;
      o.x = (short)f2bf(v.x); o.y = (short)f2bf(v.y);
      o.z = (short)f2bf(v.z); o.w = (short)f2bf(v.w);
      *(short4v*)&Cs[row][k4 * 4] = o;
    }
    if (tid < 64) cAq[tid] = cumA[bh * T_ + qc * L_ + tid];
  }

  f32x4 yacc[4];
#pragma unroll
  for (int pt = 0; pt < 4; ++pt) yacc[pt] = (f32x4){0.f, 0.f, 0.f, 0.f};

  for (int kc = 0; kc <= qc; ++kc) {
    // ---- prefetch mask values for this tile-pair into registers ----
    float m_pre[16];
    {
      const float* mbase = mask + ((size_t)bh * T_ + (size_t)(qc * L_ + 16 * wv + 4 * q)) * T_ +
                           (size_t)kc * L_ + c;
#pragma unroll
      for (int tj = 0; tj < 4; ++tj)
#pragma unroll
        for (int r = 0; r < 4; ++r)
          m_pre[tj * 4 + r] = mbase[(size_t)r * T_ + 16 * tj];
    }

    __syncthreads();  // previous iteration done reading Bs/Xt

    // ---- stage key tile: B (bf16), x^T (bf16), cumA ----
    {
      const float* Bg = Bm + ((size_t)(b * T_ + kc * L_) * H_ + h) * N_;
#pragma unroll
      for (int it = 0; it < 8; ++it) {
        const int idx = tid + 256 * it;
        const int row = idx >> 5, k4 = idx & 31;
        const float4 v = *(const float4*)(Bg + (size_t)row * (H_ * N_) + k4 * 4);
        short4v o;
        o.x = (short)f2bf(v.x); o.y = (short)f2bf(v.y);
        o.z = (short)f2bf(v.z); o.w = (short)f2bf(v.w);
        *(short4v*)&Bs[row][k4 * 4] = o;
      }
      const float* xg = x + ((size_t)(b * T_ + kc * L_) * H_ + h) * P_;
#pragma unroll
      for (int it = 0; it < 4; ++it) {
        const int idx = tid + 256 * it;        // float4 index, 1024 total
        const int j = idx >> 4, p4 = idx & 15;
        const float4 v = *(const float4*)(xg + (size_t)j * (H_ * P_) + p4 * 4);
        Xt[p4 * 4 + 0][j] = (short)f2bf(v.x);
        Xt[p4 * 4 + 1][j] = (short)f2bf(v.y);
        Xt[p4 * 4 + 2][j] = (short)f2bf(v.z);
        Xt[p4 * 4 + 3][j] = (short)f2bf(v.w);
      }
      if (tid < 64) cAk[tid] = cumA[bh * T_ + kc * L_ + tid];
    }
    __syncthreads();

    // ---- S = C . B^T via MFMA: wave strip rows 16wv..16wv+15, 4 col tiles ----
    f32x4 sacc[4];
#pragma unroll
    for (int tj = 0; tj < 4; ++tj) sacc[tj] = (f32x4){0.f, 0.f, 0.f, 0.f};
#pragma unroll
    for (int kt = 0; kt < 4; ++kt) {
      const int k0 = kt * 32;
      const short8 af = *(const short8*)&Cs[16 * wv + c][k0 + 8 * q];
#pragma unroll
      for (int tj = 0; tj < 4; ++tj) {
        const short8 bf = *(const short8*)&Bs[16 * tj + c][k0 + 8 * q];
        sacc[tj] = __builtin_amdgcn_mfma_f32_16x16x32_bf16(af, bf, sacc[tj], 0, 0, 0);
      }
    }

    // ---- weight S -> P (bf16) into LDS ----
    float ca_i[4], ck_j[4];
#pragma unroll
    for (int r = 0; r < 4; ++r) ca_i[r] = cAq[16 * wv + 4 * q + r];
#pragma unroll
    for (int tj = 0; tj < 4; ++tj) ck_j[tj] = cAk[16 * tj + c];
    const bool diag = (kc == qc);
#pragma unroll
    for (int tj = 0; tj < 4; ++tj) {
      const int j_l = 16 * tj + c;
#pragma unroll
      for (int r = 0; r < 4; ++r) {
        const int i_l = 16 * wv + 4 * q + r;
        float wgt = __expf(ca_i[r] - ck_j[tj]) + msf * m_pre[tj * 4 + r];
        if (diag && j_l > i_l) wgt = 0.0f;
        Ps[i_l][j_l] = (short)f2bf(sacc[tj][r] * wgt);
      }
    }
    __syncthreads();  // Ps strips visible (also orders vs PV reads)

    // ---- Y += P . x via MFMA ----
#pragma unroll
    for (int kt = 0; kt < 2; ++kt) {
      const int k0 = kt * 32;
      const short8 pf = *(const short8*)&Ps[16 * wv + c][k0 + 8 * q];
#pragma unroll
      for (int pt = 0; pt < 4; ++pt) {
        const short8 xf = *(const short8*)&Xt[16 * pt + c][k0 + 8 * q];
        yacc[pt] = __builtin_amdgcn_mfma_f32_16x16x32_bf16(pf, xf, yacc[pt], 0, 0, 0);
      }
    }
  }

  // ---- write Y: lane holds Y[16wv+4q+r][16pt+c] ----
  float* Yg = Y + ((size_t)(b * T_ + qc * L_) * H_ + h) * P_;
#pragma unroll
  for (int pt = 0; pt < 4; ++pt)
#pragma unroll
    for (int r = 0; r < 4; ++r)
      Yg[(size_t)(16 * wv + 4 * q + r) * (H_ * P_) + 16 * pt + c] = yacc[pt][r];
}

// ---------------------------------------------------------------------------
// Kernel 3: final_state[b,h,p,n] = sum_t exp(cumA_{T-1}-cumA_t) B[t,n] x[t,p]
// 4-way t-split within block + LDS reduction.
// ---------------------------------------------------------------------------
__global__ __launch_bounds__(512) void state_kernel(
    const float* __restrict__ x, const float* __restrict__ Bm,
    const float* __restrict__ cumA, float* __restrict__ out) {
  const int bh = blockIdx.x;   // 64
  const int pg = blockIdx.y;   // 8 groups of 8 p
  const int b = bh >> 5, h = bh & 31;
  const int tid = threadIdx.x;
  const int n = tid & 127;
  const int th = tid >> 7;     // 0..3 t-segment
  const int pbase = pg * 8;

  __shared__ float wsh[1024];
  __shared__ float red[3][8][128];
  {
    const float cend = cumA[bh * T_ + (T_ - 1)];
    for (int t = tid; t < 1024; t += 512)
      wsh[t] = __expf(cend - cumA[bh * T_ + t]);
  }
  __syncthreads();

  float acc[8];
#pragma unroll
  for (int pp = 0; pp < 8; ++pp) acc[pp] = 0.0f;

  const int t0 = th * 256;
#pragma unroll 4
  for (int it = 0; it < 256; ++it) {
    const int t = t0 + it;
    const float bv = Bm[((size_t)(b * T_ + t) * H_ + h) * N_ + n] * wsh[t];
    const float* xp = x + ((size_t)(b * T_ + t) * H_ + h) * P_ + pbase;
#pragma unroll
    for (int pp = 0; pp < 8; ++pp) acc[pp] += bv * xp[pp];
  }

  if (th > 0) {
#pragma unroll
    for (int pp = 0; pp < 8; ++pp) red[th - 1][pp][n] = acc[pp];
  }
  __syncthreads();
  if (th == 0) {
    float* o = out + (size_t)bh * P_ * N_;
#pragma unroll
    for (int pp = 0; pp < 8; ++pp) {
      const float s = acc[pp] + red[0][pp][n] + red[1][pp][n] + red[2][pp][n];
      o[(size_t)(pbase + pp) * N_ + n] = s;
    }
  }
}

// ---------------------------------------------------------------------------
extern "C" void kernel_launch(void* const* d_in, const int* in_sizes, int n_in,
                              void* d_out, int out_size, void* d_ws, size_t ws_size,
                              hipStream_t stream) {
  const float* x    = (const float*)d_in[0];
  const float* A    = (const float*)d_in[1];
  const float* Bm   = (const float*)d_in[2];
  const float* Cm   = (const float*)d_in[3];
  const float* mask = (const float*)d_in[4];
  const float* msf  = (const float*)d_in[5];
  float* Y  = (float*)d_out;
  float* fs = (float*)d_out + (size_t)2 * T_ * H_ * P_;
  float* cumA = (float*)d_ws;   // 64*1024 floats

  cuma_kernel<<<64, 1024, 0, stream>>>(A, cumA);
  attn_kernel<<<dim3(16, 64), 256, 0, stream>>>(x, Bm, Cm, mask, msf, cumA, Y);
  state_kernel<<<dim3(64, 8), 512, 0, stream>>>(x, Bm, cumA, fs);
}

// Round 3
// 538.965 us; speedup vs baseline: 2.3857x; 1.0011x over previous
//
#include <hip/hip_runtime.h>

#define T_ 1024
#define H_ 32
#define P_ 64
#define N_ 128
#define L_ 64

typedef float f32x4 __attribute__((ext_vector_type(4)));
typedef short short8 __attribute__((ext_vector_type(8)));
typedef short short4v __attribute__((ext_vector_type(4)));

static __device__ __forceinline__ unsigned short f2bf(float f) {
  unsigned int u = __float_as_uint(f);
  u += 0x7fffu + ((u >> 16) & 1u);
  return (unsigned short)(u >> 16);
}
static __device__ __forceinline__ float bf2f(short s) {
  return __uint_as_float(((unsigned int)(unsigned short)s) << 16);
}

// ---------------------------------------------------------------------------
// Kernel 1: inclusive cumsum of A over t, per (b,h).
// ---------------------------------------------------------------------------
__global__ __launch_bounds__(1024) void cuma_kernel(const float* __restrict__ A,
                                                    float* __restrict__ cumA) {
  const int bh = blockIdx.x;
  const int b = bh >> 5, h = bh & 31;
  const int t = threadIdx.x;
  __shared__ float s[1024];
  s[t] = A[(b * T_ + t) * H_ + h];
  __syncthreads();
  for (int off = 1; off < 1024; off <<= 1) {
    float v = (t >= off) ? s[t - off] : 0.0f;
    __syncthreads();
    s[t] += v;
    __syncthreads();
  }
  cumA[bh * T_ + t] = s[t];
}

// ---------------------------------------------------------------------------
// prep_b: B fp32 (b,t,h,n) -> Bbf bf16 [bh][t][n]  AND  BT bf16 [bh][n][t]
// ---------------------------------------------------------------------------
__global__ __launch_bounds__(256) void prep_b(const float* __restrict__ Bm,
                                              short* __restrict__ Bbf,
                                              short* __restrict__ BT) {
  const int bh = blockIdx.x;   // 64
  const int tb = blockIdx.y;   // 16 blocks of 64 t
  const int b = bh >> 5, h = bh & 31;
  const int tid = threadIdx.x;
  __shared__ short Bt[128][72];
#pragma unroll
  for (int i = 0; i < 8; ++i) {
    const int idx = tid + 256 * i;  // 2048 float4 chunks
    const int row = idx >> 5, n4 = idx & 31;
    const float4 v = *(const float4*)(Bm + ((size_t)(b * T_ + tb * 64 + row) * H_ + h) * N_ + n4 * 4);
    short4v o;
    o.x = (short)f2bf(v.x); o.y = (short)f2bf(v.y);
    o.z = (short)f2bf(v.z); o.w = (short)f2bf(v.w);
    *(short4v*)(Bbf + ((size_t)bh * T_ + tb * 64 + row) * N_ + n4 * 4) = o;
    Bt[n4 * 4 + 0][row] = o.x; Bt[n4 * 4 + 1][row] = o.y;
    Bt[n4 * 4 + 2][row] = o.z; Bt[n4 * 4 + 3][row] = o.w;
  }
  __syncthreads();
#pragma unroll
  for (int i = 0; i < 4; ++i) {
    const int idx = tid + 256 * i;  // 1024 short8 chunks
    const int n = idx >> 3, t8 = idx & 7;
    const short4v a = *(const short4v*)&Bt[n][t8 * 8];
    const short4v c = *(const short4v*)&Bt[n][t8 * 8 + 4];
    short8 o;
    o[0] = a.x; o[1] = a.y; o[2] = a.z; o[3] = a.w;
    o[4] = c.x; o[5] = c.y; o[6] = c.z; o[7] = c.w;
    *(short8*)(BT + ((size_t)bh * N_ + n) * T_ + tb * 64 + t8 * 8) = o;
  }
}

// ---------------------------------------------------------------------------
// prep_x: x fp32 (b,t,h,p) -> xT bf16 [bh][p][t]
// ---------------------------------------------------------------------------
__global__ __launch_bounds__(256) void prep_x(const float* __restrict__ x,
                                              short* __restrict__ xT) {
  const int bh = blockIdx.x, tb = blockIdx.y;
  const int b = bh >> 5, h = bh & 31;
  const int tid = threadIdx.x;
  __shared__ short Xt[64][72];
#pragma unroll
  for (int i = 0; i < 4; ++i) {
    const int idx = tid + 256 * i;  // 1024 float4 chunks
    const int row = idx >> 4, p4 = idx & 15;
    const float4 v = *(const float4*)(x + ((size_t)(b * T_ + tb * 64 + row) * H_ + h) * P_ + p4 * 4);
    Xt[p4 * 4 + 0][row] = (short)f2bf(v.x);
    Xt[p4 * 4 + 1][row] = (short)f2bf(v.y);
    Xt[p4 * 4 + 2][row] = (short)f2bf(v.z);
    Xt[p4 * 4 + 3][row] = (short)f2bf(v.w);
  }
  __syncthreads();
#pragma unroll
  for (int i = 0; i < 2; ++i) {
    const int idx = tid + 256 * i;  // 512 short8 chunks
    const int p = idx >> 3, t8 = idx & 7;
    const short4v a = *(const short4v*)&Xt[p][t8 * 8];
    const short4v c = *(const short4v*)&Xt[p][t8 * 8 + 4];
    short8 o;
    o[0] = a.x; o[1] = a.y; o[2] = a.z; o[3] = a.w;
    o[4] = c.x; o[5] = c.y; o[6] = c.z; o[7] = c.w;
    *(short8*)(xT + ((size_t)bh * P_ + p) * T_ + tb * 64 + t8 * 8) = o;
  }
}

// ---------------------------------------------------------------------------
// attn: barrier-free, wave-independent. Block = 4 waves of one (qc,bh);
// wave w owns S/Y rows 16w..16w+15 of the chunk. All MFMA fragments loaded
// directly from global bf16 (L2/L3-resident). Only LDS use: wave-private Ps
// round-trip (C/D layout -> A-operand layout), no __syncthreads anywhere.
// ---------------------------------------------------------------------------
__global__ __launch_bounds__(256, 4) void attn_kernel(
    const short* __restrict__ xT, const short* __restrict__ Bbf,
    const float* __restrict__ Cm, const float* __restrict__ mask,
    const float* __restrict__ msf_p, const float* __restrict__ cumA,
    float* __restrict__ Y) {
  const int blk = blockIdx.x;       // 1024
  const int qc = 15 - (blk >> 6);   // heavy jobs dispatch first
  const int bh = blk & 63;
  const int b = bh >> 5, h = bh & 31;
  const float msf = msf_p[0];
  const int tid = threadIdx.x;
  const int w = tid >> 6;           // wave -> row strip 16w..16w+15
  const int lane = tid & 63;
  const int q = lane >> 4, c = lane & 15;

  __shared__ short Ps[4][16][72];   // wave-private strips (stride 144B, 16B-aligned)

  // ---- C fragments, once per job (fp32 load + convert) ----
  short8 cf[4];
  {
    const float* Cg = Cm + ((size_t)(b * T_ + qc * L_ + 16 * w + c) * H_ + h) * N_ + 8 * q;
#pragma unroll
    for (int kt = 0; kt < 4; ++kt) {
      const float4 v0 = *(const float4*)(Cg + kt * 32);
      const float4 v1 = *(const float4*)(Cg + kt * 32 + 4);
      short8 f;
      f[0] = (short)f2bf(v0.x); f[1] = (short)f2bf(v0.y);
      f[2] = (short)f2bf(v0.z); f[3] = (short)f2bf(v0.w);
      f[4] = (short)f2bf(v1.x); f[5] = (short)f2bf(v1.y);
      f[6] = (short)f2bf(v1.z); f[7] = (short)f2bf(v1.w);
      cf[kt] = f;
    }
  }
  float ca_i[4];
#pragma unroll
  for (int r = 0; r < 4; ++r)
    ca_i[r] = cumA[bh * T_ + qc * L_ + 16 * w + 4 * q + r];

  f32x4 yacc[4];
#pragma unroll
  for (int pt = 0; pt < 4; ++pt) yacc[pt] = (f32x4){0.f, 0.f, 0.f, 0.f};

  for (int kc = 0; kc <= qc; ++kc) {
    // mask + key cumA loads (independent; latency hidden by wave TLP)
    float mv[16];
    {
      const float* mbase = mask + ((size_t)bh * T_ + (size_t)(qc * L_ + 16 * w + 4 * q)) * T_ +
                           (size_t)kc * L_ + c;
#pragma unroll
      for (int tj = 0; tj < 4; ++tj)
#pragma unroll
        for (int r = 0; r < 4; ++r)
          mv[tj * 4 + r] = mbase[(size_t)r * T_ + 16 * tj];
    }
    float ck[4];
#pragma unroll
    for (int tj = 0; tj < 4; ++tj)
      ck[tj] = cumA[bh * T_ + kc * L_ + 16 * tj + c];

    // ---- S = C . B^T (bf16 frags straight from global) ----
    f32x4 sacc[4];
#pragma unroll
    for (int tj = 0; tj < 4; ++tj) sacc[tj] = (f32x4){0.f, 0.f, 0.f, 0.f};
    const short* Bg = Bbf + ((size_t)bh * T_ + kc * L_) * N_ + 8 * q;
#pragma unroll
    for (int kt = 0; kt < 4; ++kt) {
#pragma unroll
      for (int tj = 0; tj < 4; ++tj) {
        const short8 bf = *(const short8*)(Bg + (size_t)(16 * tj + c) * N_ + kt * 32);
        sacc[tj] = __builtin_amdgcn_mfma_f32_16x16x32_bf16(cf[kt], bf, sacc[tj], 0, 0, 0);
      }
    }

    // ---- weight -> Ps (wave-private; no barrier) ----
    const bool diag = (kc == qc);
#pragma unroll
    for (int tj = 0; tj < 4; ++tj) {
      const int j_l = 16 * tj + c;
#pragma unroll
      for (int r = 0; r < 4; ++r) {
        const int i_l = 16 * w + 4 * q + r;  // chunk-local row
        float wgt = __expf(ca_i[r] - ck[tj]) + msf * mv[tj * 4 + r];
        if (diag && j_l > i_l) wgt = 0.0f;
        Ps[w][4 * q + r][j_l] = (short)f2bf(sacc[tj][r] * wgt);
      }
    }

    // ---- Y += P . x (xT bf16 frags straight from global) ----
#pragma unroll
    for (int kt2 = 0; kt2 < 2; ++kt2) {
      const short8 pf = *(const short8*)&Ps[w][c][kt2 * 32 + 8 * q];
      const short* xg = xT + (size_t)bh * P_ * T_ + kc * L_ + kt2 * 32 + 8 * q;
#pragma unroll
      for (int pt = 0; pt < 4; ++pt) {
        const short8 xf = *(const short8*)(xg + (size_t)(16 * pt + c) * T_);
        yacc[pt] = __builtin_amdgcn_mfma_f32_16x16x32_bf16(pf, xf, yacc[pt], 0, 0, 0);
      }
    }
  }

  // ---- write Y: lane holds Y[16w+4q+r][16pt+c] ----
  float* Yg = Y + ((size_t)(b * T_ + qc * L_ + 16 * w + 4 * q) * H_ + h) * P_;
#pragma unroll
  for (int pt = 0; pt < 4; ++pt)
#pragma unroll
    for (int r = 0; r < 4; ++r)
      Yg[(size_t)r * (H_ * P_) + 16 * pt + c] = yacc[pt][r];
}

// ---------------------------------------------------------------------------
// state: final_state[p][n] = sum_t (w_t * x[t,p]) * B[t,n], w_t=exp(cA_end-cA_t)
// MFMA over precomputed xT/BT. 64 blocks x 8 waves (4 p-strips x 2 t-halves).
// ---------------------------------------------------------------------------
__global__ __launch_bounds__(512) void state_kernel(
    const short* __restrict__ xT, const short* __restrict__ BT,
    const float* __restrict__ cumA, float* __restrict__ out) {
  const int bh = blockIdx.x;
  const int tid = threadIdx.x;
  const int w = (tid >> 6) & 3;   // p strip
  const int th = tid >> 8;        // t half
  const int lane = tid & 63;
  const int q = lane >> 4, c = lane & 15;

  __shared__ float wsh[1024];
  __shared__ float red[4][16][128];
  {
    const float cend = cumA[bh * T_ + (T_ - 1)];
    for (int t = tid; t < 1024; t += 512)
      wsh[t] = __expf(cend - cumA[bh * T_ + t]);
  }
  __syncthreads();

  f32x4 acc[8];
#pragma unroll
  for (int nt = 0; nt < 8; ++nt) acc[nt] = (f32x4){0.f, 0.f, 0.f, 0.f};

  for (int ktl = 0; ktl < 16; ++ktl) {
    const int t0 = th * 512 + ktl * 32;
    // A-frag: w-weighted xT
    const short8 xv = *(const short8*)(xT + ((size_t)bh * P_ + 16 * w + c) * T_ + t0 + 8 * q);
    const float4 w0 = *(const float4*)&wsh[t0 + 8 * q];
    const float4 w1 = *(const float4*)&wsh[t0 + 8 * q + 4];
    short8 af;
    af[0] = (short)f2bf(bf2f(xv[0]) * w0.x); af[1] = (short)f2bf(bf2f(xv[1]) * w0.y);
    af[2] = (short)f2bf(bf2f(xv[2]) * w0.z); af[3] = (short)f2bf(bf2f(xv[3]) * w0.w);
    af[4] = (short)f2bf(bf2f(xv[4]) * w1.x); af[5] = (short)f2bf(bf2f(xv[5]) * w1.y);
    af[6] = (short)f2bf(bf2f(xv[6]) * w1.z); af[7] = (short)f2bf(bf2f(xv[7]) * w1.w);
#pragma unroll
    for (int nt = 0; nt < 8; ++nt) {
      const short8 bf = *(const short8*)(BT + ((size_t)bh * N_ + 16 * nt + c) * T_ + t0 + 8 * q);
      acc[nt] = __builtin_amdgcn_mfma_f32_16x16x32_bf16(af, bf, acc[nt], 0, 0, 0);
    }
  }

  if (th == 1) {
#pragma unroll
    for (int nt = 0; nt < 8; ++nt)
#pragma unroll
      for (int r = 0; r < 4; ++r) red[w][4 * q + r][16 * nt + c] = acc[nt][r];
  }
  __syncthreads();
  if (th == 0) {
    float* o = out + (size_t)bh * P_ * N_;
#pragma unroll
    for (int nt = 0; nt < 8; ++nt)
#pragma unroll
      for (int r = 0; r < 4; ++r)
        o[(size_t)(16 * w + 4 * q + r) * N_ + 16 * nt + c] =
            acc[nt][r] + red[w][4 * q + r][16 * nt + c];
  }
}

// ---------------------------------------------------------------------------
extern "C" void kernel_launch(void* const* d_in, const int* in_sizes, int n_in,
                              void* d_out, int out_size, void* d_ws, size_t ws_size,
                              hipStream_t stream) {
  const float* x    = (const float*)d_in[0];
  const float* A    = (const float*)d_in[1];
  const float* Bm   = (const float*)d_in[2];
  const float* Cm   = (const float*)d_in[3];
  const float* mask = (const float*)d_in[4];
  const float* msf  = (const float*)d_in[5];
  float* Y  = (float*)d_out;
  float* fs = (float*)d_out + (size_t)2 * T_ * H_ * P_;

  char* ws = (char*)d_ws;
  float* cumA = (float*)ws;                               // 256 KB
  short* Bbf  = (short*)(ws + (1 << 18));                 // 16.8 MB
  short* BT   = (short*)(ws + (1 << 18) + (size_t)64 * T_ * N_ * 2);
  short* xT   = (short*)(ws + (1 << 18) + (size_t)128 * T_ * N_ * 2);

  cuma_kernel<<<64, 1024, 0, stream>>>(A, cumA);
  prep_b<<<dim3(64, 16), 256, 0, stream>>>(Bm, Bbf, BT);
  prep_x<<<dim3(64, 16), 256, 0, stream>>>(x, xT);
  attn_kernel<<<1024, 256, 0, stream>>>(xT, Bbf, Cm, mask, msf, cumA, Y);
  state_kernel<<<64, 512, 0, stream>>>(xT, BT, cumA, fs);
}